// Round 7
// baseline (768.935 us; speedup 1.0000x reference)
//
#include <hip/hip_runtime.h>
#include <stdint.h>

#define KCODES 8192
#define DIM 256
#define BM 64            // rows per block; waves: 2 row-halves x 2 col-halves
#define BN 128           // codebook cols per kt tile
#define NTHREADS 256
#define NKT (KCODES / BN)   // 64 tiles
#define NQP (NKT * 4)       // 256 pair-steps (64 d each)

typedef _Float16 h16;
typedef __attribute__((ext_vector_type(8))) _Float16 f16x8;
typedef __attribute__((ext_vector_type(16))) float f32x16;

__device__ __forceinline__ void split8(const float* __restrict__ x, f16x8& h, f16x8& l) {
    #pragma unroll
    for (int i = 0; i < 8; ++i) {
        float v = x[i];
        _Float16 hv = (_Float16)v;          // RNE
        h[i] = hv;
        l[i] = (_Float16)(v - (float)hv);   // exact residual in f32, RNE to f16
    }
}

// ---------------- c2 kernel: c2h[k] = 0.5 * |codebook[k]|^2 ----------------
__global__ __launch_bounds__(256) void c2_kernel(const float* __restrict__ cb,
                                                 float* __restrict__ c2h, int K) {
    int w = (blockIdx.x * blockDim.x + threadIdx.x) >> 6;
    int lane = threadIdx.x & 63;
    if (w >= K) return;
    const float4 v = *(const float4*)(cb + (size_t)w * DIM + lane * 4);
    float s = v.x * v.x + v.y * v.y + v.z * v.z + v.w * v.w;
    #pragma unroll
    for (int off = 32; off > 0; off >>= 1) s += __shfl_down(s, off);
    if (lane == 0) c2h[w] = 0.5f * s;
}

// ---------------- pack kernel: codebook -> pre-split, pre-swizzled image ----
// 512 chunk-blocks of 16 KB; chunk-block (kt*8+chunk) at h16 offset
// col*64 + p*8 holds: s = p ^ (col&7); s<4 -> f16-high of d [chunk*32+s*8..+7]
// of code kt*128+col; s>=4 -> f16-low residual. (Unchanged from R5/R6.)
__global__ __launch_bounds__(256) void pack_kernel(const float* __restrict__ cb,
                                                   h16* __restrict__ Bp) {
    const int tid = blockIdx.x * 256 + threadIdx.x;
    const int code = tid >> 5;
    const int grp = tid & 31;
    float x[8];
    *(float4*)&x[0] = *(const float4*)(cb + (size_t)code * DIM + grp * 8);
    *(float4*)&x[4] = *(const float4*)(cb + (size_t)code * DIM + grp * 8 + 4);
    f16x8 hh, ll;
    split8(x, hh, ll);
    const int kt = code >> 7, col = code & 127;
    const int chunk = grp >> 2, s = grp & 3;
    const int ph = s ^ (col & 7), pl = (s + 4) ^ (col & 7);
    h16* base = Bp + ((size_t)(kt * 8 + chunk) * 8192) + col * 64;
    *(f16x8*)(base + ph * 8) = hh;
    *(f16x8*)(base + pl * 8) = ll;
}

// ---------------- main MFMA kernel ----------------
// 32x32x16 f16 MFMA. Wave tile 32 rows x 64 cols (2 n-subtiles of 32).
// A pre-split in regs (8 chunks x 2 ksteps x h,l = 128 VGPR). B streams via
// global_load_lds into a 2x32KB double buffer, 64 d per barrier-step
// (T3 minimum-2-phase; vmcnt(0) is ~free after a full-step flight time).
// 3-pass split product (hh + hl + lh; ll term ~1e-6 << top-2 gaps ~1e-2).
__global__ __launch_bounds__(NTHREADS, 2) void vq_mfma_pk(
    const float* __restrict__ rep, const h16* __restrict__ Bp,
    const float* __restrict__ c2h, int* __restrict__ out) {

    __shared__ __align__(16) h16 buf[2][16384];   // 2 x 32 KB

    const int t = threadIdx.x;
    const int lane = t & 63;
    const int l31 = lane & 31;
    const int kh = lane >> 5;             // k-half 0/1 (8 d each)
    const int w = t >> 6;
    const int wrow = (w >> 1) * 32;       // row half: waves {0,1}->0, {2,3}->32
    const int wcol = (w & 1) * 64;        // col half: waves {0,2}->0, {1,3}->64
    const int row0 = blockIdx.x * BM;

    // ---- A fragments: row = wrow + l31, k = kh*8 + j within each kstep ----
    f16x8 ah[8][2], al[8][2];
    {
        const float* ar = rep + (size_t)(row0 + wrow + l31) * DIM + kh * 8;
        #pragma unroll
        for (int ch = 0; ch < 8; ++ch)
            #pragma unroll
            for (int ks = 0; ks < 2; ++ks) {
                float x[8];
                *(float4*)&x[0] = *(const float4*)(ar + ch * 32 + ks * 16);
                *(float4*)&x[4] = *(const float4*)(ar + ch * 32 + ks * 16 + 4);
                split8(x, ah[ch][ks], al[ch][ks]);
            }
    }

    f32x16 acc[2];
    float best[16], cc[2];
    int bidx[16];
    #pragma unroll
    for (int n = 0; n < 2; ++n)
        #pragma unroll
        for (int r = 0; r < 16; ++r) acc[n][r] = 0.f;
    #pragma unroll
    for (int r = 0; r < 16; ++r) { best[r] = -3.4e38f; bidx[r] = 0; }

    auto issuePair = [&](int p, int b) {   // stage 32 KB (2 chunks) into buf[b]
        const h16* src = Bp + (size_t)p * 16384 + t * 8;
        h16* dst = &buf[b][t * 8];
        #pragma unroll
        for (int i = 0; i < 8; ++i)
            __builtin_amdgcn_global_load_lds(
                (const __attribute__((address_space(1))) uint32_t*)(src + i * 2048),
                (__attribute__((address_space(3))) uint32_t*)(dst + i * 2048),
                16, 0, 0);
    };

    issuePair(0, 0);

    #pragma unroll 1
    for (int kt = 0; kt < NKT; ++kt) {
        const int ktbase = kt * BN;
        #pragma unroll
        for (int pp = 0; pp < 4; ++pp) {               // compile-time sub-index
            const int p = kt * 4 + pp;
            const int cur = pp & 1;                    // == p & 1
            // pair p's 8 loads were issued one full step ago -> wait is cheap.
            asm volatile("s_waitcnt vmcnt(0) lgkmcnt(0)" ::: "memory");
            __builtin_amdgcn_s_barrier();
            __builtin_amdgcn_sched_barrier(0);

            if (pp == 0) {
                cc[0] = c2h[ktbase + wcol + l31];
                cc[1] = c2h[ktbase + wcol + 32 + l31];
            }
            if (p + 1 < NQP) issuePair(p + 1, cur ^ 1);

            #pragma unroll
            for (int half = 0; half < 2; ++half) {
                const int lc = pp * 2 + half;          // chunk 0..7, compile-time
                const h16* lb = &buf[cur][half * 8192];
                #pragma unroll
                for (int ks = 0; ks < 2; ++ks) {
                    const int sh = ks * 2 + kh;
                    #pragma unroll
                    for (int n = 0; n < 2; ++n) {
                        const int c = wcol + n * 32 + l31;
                        f16x8 bh = *(const f16x8*)&lb[c * 64 + ((sh ^ (c & 7)) << 3)];
                        f16x8 bl = *(const f16x8*)&lb[c * 64 + (((sh + 4) ^ (c & 7)) << 3)];
                        acc[n] = __builtin_amdgcn_mfma_f32_32x32x16_f16(ah[lc][ks], bh, acc[n], 0, 0, 0);
                        acc[n] = __builtin_amdgcn_mfma_f32_32x32x16_f16(ah[lc][ks], bl, acc[n], 0, 0, 0);
                        acc[n] = __builtin_amdgcn_mfma_f32_32x32x16_f16(al[lc][ks], bh, acc[n], 0, 0, 0);
                    }
                }
            }

            if (pp == 3) {   // per-kt argmin epilogue (strict '>' = np tie rule)
                #pragma unroll
                for (int n = 0; n < 2; ++n) {
                    const int col = ktbase + wcol + n * 32 + l31;
                    #pragma unroll
                    for (int r = 0; r < 16; ++r) {
                        float s2 = acc[n][r] - cc[n];
                        if (s2 > best[r]) { best[r] = s2; bidx[r] = col; }
                        acc[n][r] = 0.f;
                    }
                }
            }
        }
    }

    // ---- final reduce ----
    // Step 1: shfl across the 32 col-lanes of each half (tie -> lower idx).
    // Step 2: two col-half waves cover each row -> combine via LDS scratch.
    // buf[0] is safe: last compute step (p=255, cur=1) read buf[1] only.
    float* sv = (float*)&buf[0][0];       // [row 0..63][half 0..1]
    int* si = (int*)&buf[0][2048];
    #pragma unroll
    for (int r = 0; r < 16; ++r) {
        float bv = best[r];
        int bi = bidx[r];
        #pragma unroll
        for (int mask = 1; mask <= 16; mask <<= 1) {
            float ov = __shfl_xor(bv, mask);
            int oi = __shfl_xor(bi, mask);
            if (ov > bv || (ov == bv && oi < bi)) { bv = ov; bi = oi; }
        }
        if (l31 == 0) {
            const int rl = wrow + (r & 3) + 8 * (r >> 2) + 4 * kh;   // 0..63
            sv[rl * 2 + (w & 1)] = bv;
            si[rl * 2 + (w & 1)] = bi;
        }
    }
    __syncthreads();
    if (t < BM) {
        float va = sv[t * 2 + 0], vb = sv[t * 2 + 1];
        int ia = si[t * 2 + 0], ib = si[t * 2 + 1];
        bool pickb = (vb > va) || (vb == va && ib < ia);
        out[row0 + t] = pickb ? ib : ia;
    }
}

extern "C" void kernel_launch(void* const* d_in, const int* in_sizes, int n_in,
                              void* d_out, int out_size, void* d_ws, size_t ws_size,
                              hipStream_t stream) {
    const float* rep = (const float*)d_in[0];
    const float* cb = (const float*)d_in[1];
    const int N = in_sizes[0] / DIM;   // 65536
    const int K = in_sizes[1] / DIM;   // 8192
    float* c2h = (float*)d_ws;         // 32 KB
    h16* Bp = (h16*)((char*)d_ws + 32768);   // 8 MB (ws >= 8.4 MB, proven R5)
    int* out = (int*)d_out;

    c2_kernel<<<dim3((K * 64 + 255) / 256), dim3(256), 0, stream>>>(cb, c2h, K);
    pack_kernel<<<dim3(KCODES * 32 / 256), dim3(256), 0, stream>>>(cb, Bp);
    vq_mfma_pk<<<dim3(N / BM), dim3(NTHREADS), 0, stream>>>(rep, Bp, c2h, out);
}